// Round 1
// 97.802 us; speedup vs baseline: 1.0137x; 1.0137x over previous
//
#include <hip/hip_runtime.h>
#include <math.h>

#define NROWS 1000
#define TWO_R_N 2160.0f   // 2*RADIUS*NUM_POINTS
typedef unsigned int uint;
typedef unsigned long long ull;

__device__ __forceinline__ float wsumf(float v){
#pragma unroll
  for(int o=32;o;o>>=1) v += __shfl_xor(v,o,64);
  return v;
}
__device__ __forceinline__ float wmaxf(float v){
#pragma unroll
  for(int o=32;o;o>>=1) v = fmaxf(v,__shfl_xor(v,o,64));
  return v;
}

// 512 blocks = 64 batches x 8 prior-PAIRS; 256 threads = 4 waves (row-groups).
// No LDS staging, no chunk barriers: F is L2-resident (per-XCD working set =
// 8 batches x 312KB = 2.5MB < 4MB L2; blockIdx%8 == b%8 pins same-batch blocks
// to one XCD). Each lane reads a row element ONCE and uses it for both priors.
// Element->lane partition (q+4s, pairing s/s+9), shuffle trees, softmax sweeps,
// key packing, ballot search, selection and Phase C mirror the verified kernel
// bit-for-bit so k / top-k selection bits are unchanged.
__global__ __launch_bounds__(256,2) void clr_task(const float* __restrict__ feat,
                                                  const float* __restrict__ lab,
                                                  float* __restrict__ ws)
{
  const int b  = blockIdx.x & 63;       // same-batch blocks share an XCD (64%8==0)
  const int pg = blockIdx.x >> 6;       // prior pair 0..7
  const float* __restrict__ F  = feat + (size_t)b*NROWS*78;
  const float* __restrict__ PA = lab + ((size_t)b*16 + pg*2)*78;
  const float* __restrict__ PB = PA + 78;

  __shared__ float sS [2][NROWS];       // per-prior S            (8000 B)
  __shared__ float sRT[2][NROWS];       // per-prior r*t          (8000 B)
  __shared__ float sC0[NROWS], sC1[NROWS]; // logits cols         (8000 B)
  __shared__ float red[4][8];
  __shared__ int   selIdx[2][64];

  const int tid=threadIdx.x, wave=tid>>6, lane=tid&63;
  const int rloc16=lane>>2, q=lane&3;

  // prior fragments, same per-lane partition as the row reads
  float pva[18], pvb[18];
#pragma unroll
  for(int s=0;s<18;++s){ pva[s]=PA[6+q+4*s]; pvb[s]=PB[6+q+4*s]; }
  const float2* PA2=(const float2*)PA;
  const float2* PB2=(const float2*)PB;
  const float2 a01=PA2[0], a23=PA2[1], a45=PA2[2];
  const float2 b01=PB2[0], b23=PB2[1], b45=PB2[2];

  float accR0=0.f,accT0=0.f,accD0=0.f,accL0=0.f;
  float accR1=0.f,accT1=0.f,accD1=0.f,accL1=0.f;

  // ---- Phase A: stream rows from L1/L2, both priors per read ----
#pragma unroll 2
  for(int pass=0; pass<16; ++pass){
    const int rr = pass*64 + wave*16 + rloc16;   // same per-lane row set as before
    if(rr < NROWS){
      const float* __restrict__ rp = F + rr*78;
      float part0=0.f, part1=0.f;
#pragma unroll
      for(int s=0;s<9;++s){
        const float x = rp[6+q+4*s];
        const float y = rp[6+q+4*(s+9)];
        part0 += fabsf(x - pva[s]);
        part0 += fabsf(y - pva[s+9]);
        part1 += fabsf(x - pvb[s]);
        part1 += fabsf(y - pvb[s+9]);
      }
      float s1a=part0+__shfl_xor(part0,1,64);
      float S0 = s1a +__shfl_xor(s1a, 2,64);
      float s1b=part1+__shfl_xor(part1,1,64);
      float S1 = s1b +__shfl_xor(s1b, 2,64);
      if(q==0){
        sS[0][rr]=S0; sS[1][rr]=S1;
        float d0=S0*(1.f/72.f); accD0+=d0*d0;
        accL0 += 1.f-(TWO_R_N-S0)/(TWO_R_N+S0+1e-9f);
        float d1=S1*(1.f/72.f); accD1+=d1*d1;
        accL1 += 1.f-(TWO_R_N-S1)/(TWO_R_N+S1+1e-9f);
      } else if(q==1){
        const float2* rp2=(const float2*)rp;     // 312*rr + {8,16}: 8B-aligned
        const float2 c23=rp2[1], c45=rp2[2];
        float dr3=c23.y-a23.y, dr4=c45.x-a45.x, tt=c45.y-a45.y;
        float r2=dr3*dr3+dr4*dr4;
        sRT[0][rr]=sqrtf(r2)*tt; accR0+=r2; accT0+=tt*tt;
        dr3=c23.y-b23.y; dr4=c45.x-b45.x; tt=c45.y-b45.y;
        r2=dr3*dr3+dr4*dr4;
        sRT[1][rr]=sqrtf(r2)*tt; accR1+=r2; accT1+=tt*tt;
      } else if(q==2){
        const float2* rp2=(const float2*)rp;
        const float2 c01=rp2[0];
        sC0[rr]=c01.x; sC1[rr]=c01.y;
      }
    }
  }

  // ---- cross-wave reduction (xor-tree identical to verified kernel) ----
  {
    float vR0=wsumf(accR0), vT0=wsumf(accT0), vD0=wsumf(accD0), vL0=wsumf(accL0);
    float vR1=wsumf(accR1), vT1=wsumf(accT1), vD1=wsumf(accD1), vL1=wsumf(accL1);
    if(lane==0){
      red[wave][0]=vR0; red[wave][1]=vT0; red[wave][2]=vD0; red[wave][3]=vL0;
      red[wave][4]=vR1; red[wave][5]=vT1; red[wave][6]=vD1; red[wave][7]=vL1;
    }
  }
  __syncthreads();                       // the ONLY barrier
  if(wave>=2) return;                    // waves 0/1 = tail for prior 0/1
  const int w = wave;

  float R=0.f,T=0.f,D=0.f,L=0.f;
#pragma unroll
  for(int g=0;g<4;++g){                  // same row-group combine order
    R+=red[g][4*w]; T+=red[g][4*w+1]; D+=red[g][4*w+2]; L+=red[g][4*w+3];
  }
  float Nr=fmaxf(sqrtf(R),1e-12f), Nt=fmaxf(sqrtf(T),1e-12f), Nd=fmaxf(sqrtf(D),1e-12f);
  const float inv = 1.f/(Nr*Nt*Nd);
  int k=(int)L; if(k<1)k=1; if(k>64)k=64;   // trunc == astype(int32)

  // ---- column log-softmax over 1000 rows (stride-1, conflict-free) ----
  float m0=-INFINITY, m1=-INFINITY;
#pragma unroll
  for(int t=0;t<16;++t){ int i=t*64+lane; if(i<NROWS){ m0=fmaxf(m0,sC0[i]); m1=fmaxf(m1,sC1[i]); } }
  m0=wmaxf(m0); m1=wmaxf(m1);
  float s0=0.f, s1=0.f;
#pragma unroll
  for(int t=0;t<16;++t){ int i=t*64+lane; if(i<NROWS){ s0+=__expf(sC0[i]-m0); s1+=__expf(sC1[i]-m1); } }
  s0=wsumf(s0); s1=wsumf(s1);
  const float lse0=m0+__logf(s0), lse1=m1+__logf(s1);

  const float2 p01 = w ? b01 : a01;
  const float2 p23 = w ? b23 : a23;
  const float2 p45 = w ? b45 : a45;

  // ---- per-row cost -> monotone keys (16 per lane) ----
  uint key[16];
  const float p0=p01.x, pp1=p01.y;
#pragma unroll
  for(int t=0;t<16;++t){
    int i=t*64+lane; uint kk=0xFFFFFFFFu;        // phantom sorts above everything
    if(i<NROWS){
      float ls0=sC0[i]-lse0, ls1=sC1[i]-lse1;
      float e0=__expf(ls0), e1=__expf(ls1);
      float focal=(1.f-e0)*(1.f-e0)*ls0*p0 + (1.f-e1)*(1.f-e1)*ls1*pp1;
      float prod=sRT[w][i]*(sS[w][i]*(1.f/72.f))*inv;
      float cost=3.f*prod*prod+focal;
      uint x=__float_as_uint(cost);
      kk=(x&0x80000000u)?~x:(x|0x80000000u);
    }
    key[t]=kk;
  }

  // ---- k-th smallest: 32x 1-bit ballot binary search ----
  uint pref=0u, r=(uint)k;
  for(int s=31;s>=0;--s){
    const uint pp=pref>>s;
    uint cnt=0u;
#pragma unroll
    for(int t=0;t<16;++t) cnt += (uint)__popcll(__ballot((key[t]>>s)==pp));
    if(r>cnt){ r-=cnt; pref|=(1u<<s); }
  }
  const uint T2=pref; uint need=r;               // all <T2 plus first `need` ==T2

  // ---- selection: ballot-prefix compaction (index-ascending tie-break) ----
  const ull lmask=(1ull<<lane)-1ull;
  int base=0;
#pragma unroll
  for(int t=0;t<16;++t){
    bool lt = key[t]<T2;
    bool eq = key[t]==T2;
    ull meq=__ballot(eq);
    bool eqs = eq && ((uint)__popcll(meq&lmask)<need);
    uint teq=(uint)__popcll(meq);
    need -= (teq<need?teq:need);
    bool ssel = lt||eqs;
    ull ms=__ballot(ssel);
    if(ssel) selIdx[w][base+(int)__popcll(ms&lmask)] = t*64+lane;
    base += (int)__popcll(ms);
  }

  // ---- Phase C ----
  {
    bool act = lane<k;
    int idx = selIdx[w][act?lane:0];
    const float2* R2=(const float2*)(F+(size_t)idx*78);
    float2 g01=R2[0], g23=R2[1], g45=R2[2];
    float S = sS[w][idx];
    float mk = act?1.f:0.f;
    float n2=wsumf(g23.x*g23.x*mk), n3=wsumf(g23.y*g23.y*mk);
    float n4=wsumf(g45.x*g45.x*mk), n5=wsumf(g45.y*g45.y*mk);
    float l2=p23.x, l3=p23.y, l4=p45.x, l5=p45.y;
    float de2=fmaxf(sqrtf(n2+l2*l2),1e-12f);
    float de3=fmaxf(sqrtf(n3+l3*l3),1e-12f);
    float de4=fmaxf(sqrtf(n4+l4*l4),1e-12f);
    float de5=fmaxf(sqrtf(n5+l5*l5),1e-12f);
    float d2=g23.x/de2-l2/de2, d3=g23.y/de3-l3/de3, d4=g45.x/de4-l4/de4, d5=g45.y/de5-l5/de5;
    auto h=[](float d){ float ad=fabsf(d); return ad<1.f ? 0.5f*d*d : ad-0.5f; };
    float sl1 = 0.25f*(h(d2)+h(d3)+h(d4)+h(d5));
    float mm=fmaxf(g01.x,g01.y);
    float lsee=mm+__logf(__expf(g01.x-mm)+__expf(g01.y-mm));
    float logpt=((pp1>p0)?g01.y:g01.x)-lsee;     // tgt=argmax(prior[:2]), first-max -> 0
    float pt=__expf(logpt);
    float fl=-(1.f-pt)*(1.f-pt)*logpt;
    float ll=1.f-(TWO_R_N-S)/(TWO_R_N+S+1e-9f);
    float ssl=wsumf(sl1*mk), sll=wsumf(ll*mk), sfl=wsumf(fl*mk);
    if(lane==0){
      float invk=1.f/(float)k;
      float* o = ws + (size_t)(b*16 + pg*2 + w)*3;
      o[0]=ssl*invk; o[1]=sll*invk; o[2]=sfl*invk;
    }
  }
}

__global__ __launch_bounds__(256) void clr_finalize(const float* __restrict__ ws,
                                                    float* __restrict__ out)
{
  float a=0.f, bsum=0.f, c=0.f;
  for(int i=threadIdx.x;i<1024;i+=256){
    a    += ws[i*3+0];
    bsum += ws[i*3+1];
    c    += ws[i*3+2];
  }
  a=wsumf(a); bsum=wsumf(bsum); c=wsumf(c);
  __shared__ float r[12];
  int wave=threadIdx.x>>6, lane=threadIdx.x&63;
  if(lane==0){ r[wave*3]=a; r[wave*3+1]=bsum; r[wave*3+2]=c; }
  __syncthreads();
  if(threadIdx.x==0){
    float sa=0,sb=0,sc=0;
    for(int w2=0;w2<4;w2++){sa+=r[w2*3];sb+=r[w2*3+1];sc+=r[w2*3+2];}
    float sl1l=sa*(1.f/1024.f), ll=sb*(1.f/1024.f), fl=sc*(1.f/1024.f);
    // LW_XYTL=0.5, LW_LIOU=2.0, LW_CLS=2.0
    float loss = (sl1l>0.f ? 0.5f*sl1l : 0.f)
               + (ll  >0.f ? 2.0f*ll   : 0.f)
               + (fl  >0.f ? 2.0f*fl   : 0.f);
    out[0]=loss;
  }
}

extern "C" void kernel_launch(void* const* d_in, const int* in_sizes, int n_in,
                              void* d_out, int out_size, void* d_ws, size_t ws_size,
                              hipStream_t stream)
{
  const float* feat = (const float*)d_in[0];   // (64,1000,78) f32
  const float* lab  = (const float*)d_in[1];   // (64,16,78)  f32
  float* ws  = (float*)d_ws;                   // 1024*3 floats, fully overwritten
  float* out = (float*)d_out;
  hipLaunchKernelGGL(clr_task, dim3(512), dim3(256), 0, stream, feat, lab, ws);
  hipLaunchKernelGGL(clr_finalize, dim3(1), dim3(256), 0, stream, ws, out);
}